// Round 7
// baseline (901.016 us; speedup 1.0000x reference)
//
#include <hip/hip_runtime.h>

// ---------------------------------------------------------------------------
// LavaNetwork, bit-exact 5-plane i8 MFMA GEMM (mfma_i32_16x16x64_i8).
//   w ~ k*2^-34 (|residual| <= 2^-35, same as proven f16-3-plane), k split
//   into 5 balanced base-128 digits d_j in [-64,63] -> exact i8, exact i32
//   plane sums, exact i64 Horner + f64 bias in epilogue.
// Activations are {0,1} i8 -> staged raw via global_load_lds, no conversion.
// Double-buffered GLDS prefetch hides memory latency; 16-B chunk XOR swizzle
// (baked into global layouts) keeps LDS conflict-free.
// Fallback: round-3 proven f16 path if ws too small.
// ---------------------------------------------------------------------------

typedef int i32x4 __attribute__((ext_vector_type(4)));
typedef _Float16 f16x8 __attribute__((ext_vector_type(8)));
typedef _Float16 f16x4 __attribute__((ext_vector_type(4)));
typedef float f32x4 __attribute__((ext_vector_type(4)));

#define GLDS(g, l) __builtin_amdgcn_global_load_lds( \
    (const __attribute__((address_space(1))) void*)(g), \
    (__attribute__((address_space(3))) void*)(l), 16, 0, 0)

#define INV234 5.8207660913467407e-11   // 2^-34

// ======================= prep =======================

// w (M,K) f32 -> wp [K/64][5][M][64] i8 digit planes, 16-B chunks XOR-swizzled
// by (m&3) so GLDS-staged LDS fragment reads are bank-conflict-free.
__global__ __launch_bounds__(256) void prep_w8(const float* __restrict__ A,
                                               signed char* __restrict__ wp,
                                               int M, int K)
{
    long gt = (long)blockIdx.x * 256 + threadIdx.x;
    int kq4 = K >> 2;
    int m = (int)(gt / kq4), kq = (int)(gt % kq4);
    int k0 = kq * 4;
    int kt = k0 >> 6, kin = k0 & 63;
    int cw = ((kin >> 4) ^ m) & 3;
    float4 w = *(const float4*)&A[(long)m * K + k0];
    float wv[4] = {w.x, w.y, w.z, w.w};
    int pack[5] = {0, 0, 0, 0, 0};
#pragma unroll
    for (int e = 0; e < 4; e++) {
        long k64 = (long)rint((double)wv[e] * 17179869184.0);  // * 2^34
#pragma unroll
        for (int j = 0; j < 4; j++) {
            long r = ((k64 + 64) & 127) - 64;   // balanced digit [-64,63]
            pack[j] |= ((int)r & 255) << (e * 8);
            k64 = (k64 - r) >> 7;
        }
        pack[4] |= ((int)k64 & 255) << (e * 8); // |k64| <= 34, fits
    }
#pragma unroll
    for (int p = 0; p < 5; p++)
        *(int*)&wp[(((long)kt * 5 + p) * M + m) * 64 + cw * 16 + (kin & 15)] = pack[p];
}

// x [b][512][1024] f32 -> x8t [b][1024][512] i8 (transpose+binarize), chunk
// swizzle (c ^ (t&3)) within each 64-B k-tile.
__global__ __launch_bounds__(256) void prep_x8(const float* __restrict__ x,
                                               unsigned char* __restrict__ xt)
{
    __shared__ float xs[64][68];
    const int b = blockIdx.z, i0 = blockIdx.y * 64, t0 = blockIdx.x * 64;
    const float* xb = x + ((long)b * 512 + i0) * 1024 + t0;
#pragma unroll
    for (int p = 0; p < 4; p++) {
        int f = threadIdx.x + p * 256;
        int i = f >> 4, t4 = (f & 15) * 4;
        *(float4*)&xs[i][t4] = *(const float4*)&xb[(long)i * 1024 + t4];
    }
    __syncthreads();
    int tt = threadIdx.x >> 2, c = threadIdx.x & 3;
    int t = t0 + tt;
    int cw = c ^ (t & 3);
    unsigned char bytes[16];
#pragma unroll
    for (int j = 0; j < 16; j++)
        bytes[j] = (unsigned char)xs[c * 16 + j][tt];
    *(uint4*)&xt[((long)b * 1024 + t) * 512 + i0 + cw * 16] = *(uint4*)bytes;
}

// ======================= GEMM (both orientations) =======================
// TRANS: D[t][M]  (acts as A operand)  -> cur1t for coalesced LIF
// !TRANS: D[M][t] (weights as A operand) -> cur2 directly
// Block tile: 128t x 64m, wave tile 64t x 32m. K-step 64, double-buffered.
template <bool TRANS>
__global__ __launch_bounds__(256, 2) void gemm_i8(
    const signed char* __restrict__ wp,     // [K/64][5][M][64] swizzled
    const unsigned char* __restrict__ act,  // [b][1024][K] swizzled
    const float* __restrict__ bias,         // (M)
    float* __restrict__ C,
    int M, int K)
{
    __shared__ unsigned char As[2][128][64];   // acts   16 KB
    __shared__ signed char Ws[2][5][64][64];   // planes 40 KB

    const int b = blockIdx.z;
    const unsigned char* ab = act + (long)b * 1024 * K;
    const int tid = threadIdx.x, lane = tid & 63, wave = tid >> 6;
    const int m0 = (TRANS ? blockIdx.x : blockIdx.y) * 64;
    const int t0 = (TRANS ? blockIdx.y : blockIdx.x) * 128;
    const int wt = (wave >> 1) * 64, wm = (wave & 1) * 32;
    const int lm = lane & 15, lq = lane >> 4;
    const int fro = ((lq ^ lm) & 3) * 16;      // swizzled frag chunk offset
    const int gl_t = lane >> 2, gl_c = (lane & 3) * 16;

    i32x4 acc[5][8];
#pragma unroll
    for (int p = 0; p < 5; p++)
#pragma unroll
        for (int u = 0; u < 8; u++) acc[p][u] = (i32x4)0;

    const int niter = K >> 6;

    // stage iter 0 into buf 0
    for (int r = wave; r < 28; r += 4) {
        if (r < 8) {
            const unsigned char* g = ab + ((long)(t0 + r * 16 + gl_t)) * K + gl_c;
            GLDS(g, &As[0][r * 16][0]);
        } else {
            int q = r - 8, p = q >> 2, s = q & 3;
            const signed char* g = wp + (((long)p) * M + m0 + s * 16 + gl_t) * 64 + gl_c;
            GLDS(g, &Ws[0][p][s * 16][0]);
        }
    }
    __syncthreads();

    for (int it = 0; it < niter; it++) {
        const int buf = it & 1;
        if (it + 1 < niter) {
            const int kt = it + 1;
            for (int r = wave; r < 28; r += 4) {
                if (r < 8) {
                    const unsigned char* g =
                        ab + ((long)(t0 + r * 16 + gl_t)) * K + kt * 64 + gl_c;
                    GLDS(g, &As[buf ^ 1][r * 16][0]);
                } else {
                    int q = r - 8, p = q >> 2, s = q & 3;
                    const signed char* g =
                        wp + (((long)kt * 5 + p) * M + m0 + s * 16 + gl_t) * 64 + gl_c;
                    GLDS(g, &Ws[buf ^ 1][p][s * 16][0]);
                }
            }
        }
        i32x4 a[4];
#pragma unroll
        for (int i = 0; i < 4; i++)
            a[i] = *(const i32x4*)&As[buf][wt + i * 16 + lm][fro];
#pragma unroll
        for (int p = 0; p < 5; p++) {
            i32x4 w0 = *(const i32x4*)&Ws[buf][p][wm + lm][fro];
            i32x4 w1 = *(const i32x4*)&Ws[buf][p][wm + 16 + lm][fro];
            if (TRANS) {
#pragma unroll
                for (int i = 0; i < 4; i++) {
                    acc[p][i * 2 + 0] = __builtin_amdgcn_mfma_i32_16x16x64_i8(
                        a[i], w0, acc[p][i * 2 + 0], 0, 0, 0);
                    acc[p][i * 2 + 1] = __builtin_amdgcn_mfma_i32_16x16x64_i8(
                        a[i], w1, acc[p][i * 2 + 1], 0, 0, 0);
                }
            } else {
#pragma unroll
                for (int j = 0; j < 4; j++) {
                    acc[p][j * 2 + 0] = __builtin_amdgcn_mfma_i32_16x16x64_i8(
                        w0, a[j], acc[p][j * 2 + 0], 0, 0, 0);
                    acc[p][j * 2 + 1] = __builtin_amdgcn_mfma_i32_16x16x64_i8(
                        w1, a[j], acc[p][j * 2 + 1], 0, 0, 0);
                }
            }
        }
        __syncthreads();
    }

    if (TRANS) {
        double bv[2];
        bv[0] = (double)bias[m0 + wm + lm];
        bv[1] = (double)bias[m0 + wm + 16 + lm];
        float* Cb = C + (long)b * 1024 * M;
#pragma unroll
        for (int i = 0; i < 4; i++)
#pragma unroll
            for (int r = 0; r < 4; r++) {
                const int trow = t0 + wt + i * 16 + lq * 4 + r;
#pragma unroll
                for (int jj = 0; jj < 2; jj++) {
                    long T = acc[4][i * 2 + jj][r];
                    T = T * 128 + acc[3][i * 2 + jj][r];
                    T = T * 128 + acc[2][i * 2 + jj][r];
                    T = T * 128 + acc[1][i * 2 + jj][r];
                    T = T * 128 + acc[0][i * 2 + jj][r];
                    const int col = m0 + wm + jj * 16 + lm;
                    Cb[(long)trow * M + col] = (float)((double)T * INV234 + bv[jj]);
                }
            }
    } else {
        float* Cb = C + (long)b * M * 1024;
#pragma unroll
        for (int h = 0; h < 2; h++)
#pragma unroll
            for (int r = 0; r < 4; r++) {
                const int row = m0 + wm + h * 16 + lq * 4 + r;
                const double bv = (double)bias[row];
#pragma unroll
                for (int j = 0; j < 4; j++) {
                    long T = acc[4][j * 2 + h][r];
                    T = T * 128 + acc[3][j * 2 + h][r];
                    T = T * 128 + acc[2][j * 2 + h][r];
                    T = T * 128 + acc[1][j * 2 + h][r];
                    T = T * 128 + acc[0][j * 2 + h][r];
                    Cb[(long)row * 1024 + t0 + wt + j * 16 + lm] =
                        (float)((double)T * INV234 + bv);
                }
            }
    }
}

// ======================= LIF =======================

// Coalesced thread-per-row scan over cur1t [b][1024][2048]; emits i8 spikes
// [b][t][2048] (chunk-swizzled for GEMM2 staging) + 1024-bit masks.
__global__ __launch_bounds__(256) void lif1_t(
    const float* __restrict__ ct,
    unsigned char* __restrict__ spk8,
    unsigned* __restrict__ mask_ws)
{
    const int b = blockIdx.y;
    const int m = blockIdx.x * 256 + threadIdx.x;
    const float* src = ct + (long)b * 1024 * 2048 + m;
    unsigned char* spb = spk8 + (long)b * 1024 * 2048 + (m & ~63) + (m & 15);
    const int mch = (m >> 4) & 3;
    unsigned* mw = mask_ws + (long)b * 32 * 2048 + m;
    double v = 0.0;
    for (int tw = 0; tw < 32; tw++) {
        float c[32];
#pragma unroll
        for (int j = 0; j < 32; j++)
            c[j] = src[(long)(tw * 32 + j) * 2048];
        unsigned mword = 0;
#pragma unroll
        for (int j = 0; j < 32; j++) {
            v = 0.95 * v + (double)c[j];
            bool s = v >= 1.0;
            mword |= (s ? 1u : 0u) << j;
            if (s) v = 0.0;
            const int t = tw * 32 + j;
            spb[(long)t * 2048 + ((mch ^ (t & 3)) << 4)] = s ? 1 : 0;
        }
        mw[(long)tw * 2048] = mword;
    }
}

// masks [b][32][2048] -> f32 spikes [b][2048][1024]
__global__ __launch_bounds__(256) void expand_spk(
    const unsigned* __restrict__ mask_ws,
    float* __restrict__ spk1)
{
    __shared__ unsigned msk[8][32];
    const long rowbase = (long)blockIdx.x * 8;
    const int b = (int)(rowbase >> 11), m0 = (int)(rowbase & 2047);
    const int tid = threadIdx.x;
    {
        int w = tid >> 3, r = tid & 7;
        msk[r][w] = mask_ws[((long)b * 32 + w) * 2048 + m0 + r];
    }
    __syncthreads();
    const int r = tid >> 5, l5 = tid & 31;
    float* dst = spk1 + (rowbase + r) * 1024;
    const int sh = (l5 & 7) * 4;
#pragma unroll
    for (int j = 0; j < 8; j++) {
        const int t = l5 * 4 + j * 128;
        const unsigned w = msk[r][(l5 >> 3) + j * 4];
        float4 o;
        o.x = ((w >> sh) & 1u) ? 1.f : 0.f;
        o.y = ((w >> (sh + 1)) & 1u) ? 1.f : 0.f;
        o.z = ((w >> (sh + 2)) & 1u) ? 1.f : 0.f;
        o.w = ((w >> (sh + 3)) & 1u) ? 1.f : 0.f;
        *(float4*)&dst[t] = o;
    }
}

// LDS-chunked LIF for layer 2 (proven round 4)
template <int RPB>
__global__ __launch_bounds__(256) void lif_lds(float* __restrict__ cur)
{
    __shared__ float cs[RPB][36];
    const long rowbase = (long)blockIdx.x * RPB;
    float* base = cur + rowbase * 1024;
    const int tid = threadIdx.x;
    double v = 0.0;
    const int NV = RPB * 32 / 4;
    for (int tc = 0; tc < 1024; tc += 32) {
        for (int f = tid; f < NV; f += 256) {
            int row = f >> 3, t4 = (f & 7) * 4;
            *(float4*)&cs[row][t4] = *(const float4*)&base[(long)row * 1024 + tc + t4];
        }
        __syncthreads();
        if (tid < RPB) {
#pragma unroll
            for (int j = 0; j < 32; j++) {
                v = 0.95 * v + (double)cs[tid][j];
                bool s = v >= 1.0;
                cs[tid][j] = s ? 1.f : 0.f;
                if (s) v = 0.0;
            }
        }
        __syncthreads();
        for (int f = tid; f < NV; f += 256) {
            int row = f >> 3, t4 = (f & 7) * 4;
            *(float4*)&base[(long)row * 1024 + tc + t4] = *(float4*)&cs[row][t4];
        }
        __syncthreads();
    }
}

// ======================= fallback (round 3, proven) =======================

__device__ inline void split3(float w, _Float16& q0, _Float16& q1, _Float16& q2) {
    float p0 = rintf(w * 4096.f) * 2.44140625e-4f;
    float r1 = w - p0;
    float p1s = rintf(r1 * 8388608.f) * 2.44140625e-4f;
    float r2 = r1 - p1s * 4.8828125e-4f;
    float p2s = rintf(r2 * 1.7179869184e10f) * 1.220703125e-4f;
    q0 = (_Float16)p0; q1 = (_Float16)p1s; q2 = (_Float16)p2s;
}

__global__ __launch_bounds__(256) void gemm_f16x3_kernel(
    const float* __restrict__ A, const float* __restrict__ Bmat,
    const float* __restrict__ bias, float* __restrict__ C,
    int M, int N, int K, long sB, long sC)
{
    __shared__ _Float16 As[3][128][40];
    __shared__ _Float16 Bsh[128][40];
    const int batch = blockIdx.z;
    const float* Bp = Bmat + (long)batch * sB;
    float* Cp = C + (long)batch * sC;
    const int m0 = blockIdx.y * 128, n0 = blockIdx.x * 128;
    const int tid = threadIdx.x, lane = tid & 63, wave = tid >> 6;
    const int wrow = (wave >> 1) * 64, wcol = (wave & 1) * 64;
    const int lm = lane & 15, lq = lane >> 4;
    const int a_mo = tid >> 3, a_kc = (tid & 7) * 4;
    const int b_kq = tid >> 5, b_nq = tid & 31;

    f32x4 acc[3][4][4];
#pragma unroll
    for (int p = 0; p < 3; p++)
#pragma unroll
        for (int i = 0; i < 4; i++)
#pragma unroll
            for (int j = 0; j < 4; j++) acc[p][i][j] = (f32x4)0.f;

    for (int k0 = 0; k0 < K; k0 += 32) {
#pragma unroll
        for (int i = 0; i < 4; i++) {
            const int m = i * 32 + a_mo;
            float4 w = *(const float4*)&A[(long)(m0 + m) * K + k0 + a_kc];
            _Float16 a0[4], a1[4], a2[4];
            split3(w.x, a0[0], a1[0], a2[0]);
            split3(w.y, a0[1], a1[1], a2[1]);
            split3(w.z, a0[2], a1[2], a2[2]);
            split3(w.w, a0[3], a1[3], a2[3]);
            *(f16x4*)&As[0][m][a_kc] = (f16x4){a0[0], a0[1], a0[2], a0[3]};
            *(f16x4*)&As[1][m][a_kc] = (f16x4){a1[0], a1[1], a1[2], a1[3]};
            *(f16x4*)&As[2][m][a_kc] = (f16x4){a2[0], a2[1], a2[2], a2[3]};
        }
        {
            float4 r0 = *(const float4*)&Bp[(long)(k0 + b_kq * 4 + 0) * N + n0 + b_nq * 4];
            float4 r1 = *(const float4*)&Bp[(long)(k0 + b_kq * 4 + 1) * N + n0 + b_nq * 4];
            float4 r2 = *(const float4*)&Bp[(long)(k0 + b_kq * 4 + 2) * N + n0 + b_nq * 4];
            float4 r3 = *(const float4*)&Bp[(long)(k0 + b_kq * 4 + 3) * N + n0 + b_nq * 4];
            *(f16x4*)&Bsh[b_nq * 4 + 0][b_kq * 4] =
                (f16x4){(_Float16)r0.x, (_Float16)r1.x, (_Float16)r2.x, (_Float16)r3.x};
            *(f16x4*)&Bsh[b_nq * 4 + 1][b_kq * 4] =
                (f16x4){(_Float16)r0.y, (_Float16)r1.y, (_Float16)r2.y, (_Float16)r3.y};
            *(f16x4*)&Bsh[b_nq * 4 + 2][b_kq * 4] =
                (f16x4){(_Float16)r0.z, (_Float16)r1.z, (_Float16)r2.z, (_Float16)r3.z};
            *(f16x4*)&Bsh[b_nq * 4 + 3][b_kq * 4] =
                (f16x4){(_Float16)r0.w, (_Float16)r1.w, (_Float16)r2.w, (_Float16)r3.w};
        }
        __syncthreads();
        f16x8 bf[4];
#pragma unroll
        for (int j = 0; j < 4; j++)
            bf[j] = *(const f16x8*)&Bsh[wcol + j * 16 + lm][lq * 8];
#pragma unroll
        for (int p = 0; p < 3; p++) {
            f16x8 af[4];
#pragma unroll
            for (int i = 0; i < 4; i++)
                af[i] = *(const f16x8*)&As[p][wrow + i * 16 + lm][lq * 8];
#pragma unroll
            for (int i = 0; i < 4; i++)
#pragma unroll
                for (int j = 0; j < 4; j++)
                    acc[p][i][j] = __builtin_amdgcn_mfma_f32_16x16x32_f16(
                        af[i], bf[j], acc[p][i][j], 0, 0, 0);
        }
        __syncthreads();
    }
#pragma unroll
    for (int i = 0; i < 4; i++)
#pragma unroll
        for (int r = 0; r < 4; r++) {
            const int row = m0 + wrow + i * 16 + lq * 4 + r;
            const double bv = (double)bias[row];
#pragma unroll
            for (int j = 0; j < 4; j++) {
                double s = (double)acc[0][i][j][r]
                         + (double)acc[1][i][j][r] * 4.8828125e-4
                         + (double)acc[2][i][j][r] * 4.76837158203125e-7 + bv;
                Cp[(long)row * N + n0 + wcol + j * 16 + lm] = (float)s;
            }
        }
}

__global__ __launch_bounds__(256) void lif_rows(float* __restrict__ data,
                                                long nrows, int T)
{
    long r = (long)blockIdx.x * blockDim.x + threadIdx.x;
    if (r >= nrows) return;
    float* p = data + r * (long)T;
    double v = 0.0;
    for (int t = 0; t < T; t += 4) {
        float4 c = *(float4*)(p + t);
        float4 s;
        v = 0.95 * v + (double)c.x; s.x = (v >= 1.0) ? 1.f : 0.f; if (v >= 1.0) v = 0.0;
        v = 0.95 * v + (double)c.y; s.y = (v >= 1.0) ? 1.f : 0.f; if (v >= 1.0) v = 0.0;
        v = 0.95 * v + (double)c.z; s.z = (v >= 1.0) ? 1.f : 0.f; if (v >= 1.0) v = 0.0;
        v = 0.95 * v + (double)c.w; s.w = (v >= 1.0) ? 1.f : 0.f; if (v >= 1.0) v = 0.0;
        *(float4*)(p + t) = s;
    }
}

// ======================= launch =======================

extern "C" void kernel_launch(void* const* d_in, const int* in_sizes, int n_in,
                              void* d_out, int out_size, void* d_ws, size_t ws_size,
                              hipStream_t stream)
{
    const float* x  = (const float*)d_in[0];  // (32, 512, 1024)
    const float* w1 = (const float*)d_in[1];  // (2048, 512)
    const float* b1 = (const float*)d_in[2];  // (2048)
    const float* w2 = (const float*)d_in[3];  // (256, 2048)
    const float* b2 = (const float*)d_in[4];  // (256)

    float* out  = (float*)d_out;
    float* spk1 = out;                              // (32, 2048, 1024)
    float* spk2 = out + (long)32 * 2048 * 1024;     // (32, 256, 1024)

    const size_t WP1 = 5242880;        // [8][5][2048][64] i8
    const size_t WP2 = 2621440;        // [32][5][256][64] i8
    const size_t X8T = 16777216;       // [32][1024][512] i8
    const size_t SPK = 67108864;       // [32][1024][2048] i8
    const size_t MSK = 8388608;        // [32][32][2048] u32
    const size_t NEED = WP1 + WP2 + X8T + SPK + MSK;

    if (ws_size >= NEED) {
        char* ws = (char*)d_ws;
        signed char* wp1 = (signed char*)ws;
        signed char* wp2 = (signed char*)(ws + WP1);
        unsigned char* x8t = (unsigned char*)(ws + WP1 + WP2);
        unsigned char* spk8 = (unsigned char*)(ws + WP1 + WP2 + X8T);
        unsigned* mask_ws = (unsigned*)(ws + WP1 + WP2 + X8T + SPK);

        prep_w8<<<1024, 256, 0, stream>>>(w1, wp1, 2048, 512);
        prep_w8<<<512, 256, 0, stream>>>(w2, wp2, 256, 2048);
        prep_x8<<<dim3(16, 8, 32), 256, 0, stream>>>(x, x8t);

        // layer 1: cur1t [b][t][2048] -> coalesced LIF -> spikes
        gemm_i8<true><<<dim3(32, 8, 32), 256, 0, stream>>>(
            wp1, x8t, b1, spk1, 2048, 512);
        lif1_t<<<dim3(8, 32), 256, 0, stream>>>(spk1, spk8, mask_ws);
        expand_spk<<<8192, 256, 0, stream>>>(mask_ws, spk1);

        // layer 2: cur2 [b][256][1024] direct -> in-place LIF
        gemm_i8<false><<<dim3(8, 4, 32), 256, 0, stream>>>(
            wp2, spk8, b2, spk2, 256, 2048);
        lif_lds<128><<<64, 256, 0, stream>>>(spk2);
    } else {
        gemm_f16x3_kernel<<<dim3(8, 16, 32), 256, 0, stream>>>(
            w1, x, b1, spk1, 2048, 1024, 512, (long)512 * 1024, (long)2048 * 1024);
        lif_rows<<<(65536 + 255) / 256, 256, 0, stream>>>(spk1, 65536, 1024);
        gemm_f16x3_kernel<<<dim3(8, 2, 32), 256, 0, stream>>>(
            w2, spk1, b2, spk2, 256, 1024, 2048, (long)2048 * 1024, (long)256 * 1024);
        lif_rows<<<(8192 + 255) / 256, 256, 0, stream>>>(spk2, 8192, 1024);
    }
}

// Round 8
// 846.684 us; speedup vs baseline: 1.0642x; 1.0642x over previous
//
#include <hip/hip_runtime.h>

// ---------------------------------------------------------------------------
// LavaNetwork, bit-exact 4-plane i8 MFMA GEMM (mfma_i32_16x16x64_i8).
//   w ~ k*2^-31 (k = rint(w*2^31), residual <= 2^-32), k split into 4
//   balanced base-256 digits in [-128,127] -> exact i8 planes, exact i32
//   sums (|S| <= 2^18), exact i64 Horner + f64 bias epilogue.
// Activations {0,1} i8 staged raw via global_load_lds.
// LDS chunk swizzle: logical 16-B chunk c of row r stored at c ^ ((r>>1)&3)
// (round-6-proven conflict-free pattern for 64-B rows), baked into ALL
// global layouts so GLDS staging needs no shuffling.
// Wave tile 64t x 32m (4 t-frags x 2 m-frags x 4 planes = 32 mfma / 12 reads
// per k64). Double-buffered GLDS prefetch.
// Fallback: round-3 proven f16 path if ws too small.
// ---------------------------------------------------------------------------

typedef int i32x4 __attribute__((ext_vector_type(4)));
typedef _Float16 f16x8 __attribute__((ext_vector_type(8)));
typedef _Float16 f16x4 __attribute__((ext_vector_type(4)));
typedef float f32x4 __attribute__((ext_vector_type(4)));

#define GLDS(g, l) __builtin_amdgcn_global_load_lds( \
    (const __attribute__((address_space(1))) void*)(g), \
    (__attribute__((address_space(3))) void*)(l), 16, 0, 0)

#define INV231 4.656612873077392578125e-10   // 2^-31

// ======================= prep =======================

// w (M,K) f32 -> wp [K/64][4][M][64] i8 digit planes; 16-B chunk c of row m
// stored at c ^ ((m>>1)&3).
__global__ __launch_bounds__(256) void prep_w8(const float* __restrict__ A,
                                               signed char* __restrict__ wp,
                                               int M, int K)
{
    long gt = (long)blockIdx.x * 256 + threadIdx.x;
    int kq4 = K >> 2;
    int m = (int)(gt / kq4), kq = (int)(gt % kq4);
    int k0 = kq * 4;
    int kt = k0 >> 6, kin = k0 & 63;
    int cw = ((kin >> 4) ^ (m >> 1)) & 3;
    float4 w = *(const float4*)&A[(long)m * K + k0];
    float wv[4] = {w.x, w.y, w.z, w.w};
    int pack[4] = {0, 0, 0, 0};
#pragma unroll
    for (int e = 0; e < 4; e++) {
        long k64 = (long)rint((double)wv[e] * 2147483648.0);  // * 2^31
#pragma unroll
        for (int j = 0; j < 3; j++) {
            long r = ((k64 + 128) & 255) - 128;   // balanced digit [-128,127]
            pack[j] |= ((int)r & 255) << (e * 8);
            k64 = (k64 - r) >> 8;
        }
        pack[3] |= ((int)k64 & 255) << (e * 8);   // |k64| <= ~2^6 after 3 digits
    }
#pragma unroll
    for (int p = 0; p < 4; p++)
        *(int*)&wp[(((long)kt * 4 + p) * M + m) * 64 + cw * 16 + (kin & 15)] = pack[p];
}

// x [b][512][1024] f32 -> x8t [b][1024][512] i8 (transpose+binarize), 16-B
// chunk c within each 64-B k-tile of row t stored at c ^ ((t>>1)&3).
__global__ __launch_bounds__(256) void prep_x8(const float* __restrict__ x,
                                               unsigned char* __restrict__ xt)
{
    __shared__ float xs[64][68];
    const int b = blockIdx.z, i0 = blockIdx.y * 64, t0 = blockIdx.x * 64;
    const float* xb = x + ((long)b * 512 + i0) * 1024 + t0;
#pragma unroll
    for (int p = 0; p < 4; p++) {
        int f = threadIdx.x + p * 256;
        int i = f >> 4, t4 = (f & 15) * 4;
        *(float4*)&xs[i][t4] = *(const float4*)&xb[(long)i * 1024 + t4];
    }
    __syncthreads();
    int tt = threadIdx.x >> 2, c = threadIdx.x & 3;
    int t = t0 + tt;
    int cw = c ^ ((t >> 1) & 3);
    unsigned char bytes[16];
#pragma unroll
    for (int j = 0; j < 16; j++)
        bytes[j] = (unsigned char)xs[c * 16 + j][tt];
    *(uint4*)&xt[((long)b * 1024 + t) * 512 + i0 + cw * 16] = *(uint4*)bytes;
}

// ======================= GEMM (both orientations) =======================
// TRANS: D[t][M] (acts as A operand) -> cur1t for coalesced LIF
// !TRANS: D[M][t] (weights as A operand) -> cur2 directly
// Block 128t x 64m; 4 waves as 2t x 2m -> wave tile 64t x 32m. K-step 64.
template <bool TRANS>
__global__ __launch_bounds__(256, 2) void gemm_i8(
    const signed char* __restrict__ wp,     // [K/64][4][M][64] swizzled
    const unsigned char* __restrict__ act,  // [b][1024][K] swizzled
    const float* __restrict__ bias,         // (M)
    float* __restrict__ C,
    int M, int K)
{
    __shared__ unsigned char As[2][128][64];   // acts   16 KB
    __shared__ signed char Ws[2][4][64][64];   // planes 32 KB

    const int b = blockIdx.z;
    const unsigned char* ab = act + (long)b * 1024 * K;
    const int tid = threadIdx.x, lane = tid & 63, wave = tid >> 6;
    const int m0 = (TRANS ? blockIdx.x : blockIdx.y) * 64;
    const int t0 = (TRANS ? blockIdx.y : blockIdx.x) * 128;
    const int wt = (wave >> 1) * 64, wm = (wave & 1) * 32;
    const int lm = lane & 15, lq = lane >> 4;
    const int fro = ((lq ^ (lm >> 1)) & 3) * 16;   // round-6-proven swizzle
    const int gl_t = lane >> 2, gl_c = (lane & 3) * 16;

    i32x4 acc[4][8];
#pragma unroll
    for (int p = 0; p < 4; p++)
#pragma unroll
        for (int u = 0; u < 8; u++) acc[p][u] = (i32x4)0;

    const int niter = K >> 6;

    // stage iter 0 into buf 0: 8 act slabs + 16 weight slabs (1024 B each)
    for (int r = wave; r < 24; r += 4) {
        if (r < 8) {
            const unsigned char* g = ab + ((long)(t0 + r * 16 + gl_t)) * K + gl_c;
            GLDS(g, &As[0][r * 16][0]);
        } else {
            int q = r - 8, p = q >> 2, s = q & 3;
            const signed char* g = wp + (((long)p) * M + m0 + s * 16 + gl_t) * 64 + gl_c;
            GLDS(g, &Ws[0][p][s * 16][0]);
        }
    }
    __syncthreads();

    for (int it = 0; it < niter; it++) {
        const int buf = it & 1;
        if (it + 1 < niter) {
            const int kt = it + 1;
            for (int r = wave; r < 24; r += 4) {
                if (r < 8) {
                    const unsigned char* g =
                        ab + ((long)(t0 + r * 16 + gl_t)) * K + kt * 64 + gl_c;
                    GLDS(g, &As[buf ^ 1][r * 16][0]);
                } else {
                    int q = r - 8, p = q >> 2, s = q & 3;
                    const signed char* g =
                        wp + (((long)kt * 4 + p) * M + m0 + s * 16 + gl_t) * 64 + gl_c;
                    GLDS(g, &Ws[buf ^ 1][p][s * 16][0]);
                }
            }
        }
        i32x4 a[4];
#pragma unroll
        for (int i = 0; i < 4; i++)
            a[i] = *(const i32x4*)&As[buf][wt + i * 16 + lm][fro];
#pragma unroll
        for (int p = 0; p < 4; p++) {
            i32x4 w0 = *(const i32x4*)&Ws[buf][p][wm + lm][fro];
            i32x4 w1 = *(const i32x4*)&Ws[buf][p][wm + 16 + lm][fro];
            if (TRANS) {
#pragma unroll
                for (int i = 0; i < 4; i++) {
                    acc[p][i * 2 + 0] = __builtin_amdgcn_mfma_i32_16x16x64_i8(
                        a[i], w0, acc[p][i * 2 + 0], 0, 0, 0);
                    acc[p][i * 2 + 1] = __builtin_amdgcn_mfma_i32_16x16x64_i8(
                        a[i], w1, acc[p][i * 2 + 1], 0, 0, 0);
                }
            } else {
#pragma unroll
                for (int j = 0; j < 4; j++) {
                    acc[p][j * 2 + 0] = __builtin_amdgcn_mfma_i32_16x16x64_i8(
                        w0, a[j], acc[p][j * 2 + 0], 0, 0, 0);
                    acc[p][j * 2 + 1] = __builtin_amdgcn_mfma_i32_16x16x64_i8(
                        w1, a[j], acc[p][j * 2 + 1], 0, 0, 0);
                }
            }
        }
        __syncthreads();
    }

    if (TRANS) {
        double bv[2];
        bv[0] = (double)bias[m0 + wm + lm];
        bv[1] = (double)bias[m0 + wm + 16 + lm];
        float* Cb = C + (long)b * 1024 * M;
#pragma unroll
        for (int i = 0; i < 4; i++)
#pragma unroll
            for (int r = 0; r < 4; r++) {
                const int trow = t0 + wt + i * 16 + lq * 4 + r;
#pragma unroll
                for (int jj = 0; jj < 2; jj++) {
                    long T = acc[3][i * 2 + jj][r];
                    T = T * 256 + acc[2][i * 2 + jj][r];
                    T = T * 256 + acc[1][i * 2 + jj][r];
                    T = T * 256 + acc[0][i * 2 + jj][r];
                    const int col = m0 + wm + jj * 16 + lm;
                    Cb[(long)trow * M + col] = (float)((double)T * INV231 + bv[jj]);
                }
            }
    } else {
        float* Cb = C + (long)b * M * 1024;
#pragma unroll
        for (int h = 0; h < 2; h++)
#pragma unroll
            for (int r = 0; r < 4; r++) {
                const int row = m0 + wm + h * 16 + lq * 4 + r;
                const double bv = (double)bias[row];
#pragma unroll
                for (int j = 0; j < 4; j++) {
                    long T = acc[3][j * 2 + h][r];
                    T = T * 256 + acc[2][j * 2 + h][r];
                    T = T * 256 + acc[1][j * 2 + h][r];
                    T = T * 256 + acc[0][j * 2 + h][r];
                    Cb[(long)row * 1024 + t0 + wt + j * 16 + lm] =
                        (float)((double)T * INV231 + bv);
                }
            }
    }
}

// ======================= LIF =======================

// Coalesced thread-per-row scan over cur1t [b][1024][2048]; emits i8 spikes
// [b][t][2048] (chunk-swizzled c^((t>>1)&3) for GEMM2 staging) + masks.
__global__ __launch_bounds__(256) void lif1_t(
    const float* __restrict__ ct,
    unsigned char* __restrict__ spk8,
    unsigned* __restrict__ mask_ws)
{
    const int b = blockIdx.y;
    const int m = blockIdx.x * 256 + threadIdx.x;
    const float* src = ct + (long)b * 1024 * 2048 + m;
    unsigned char* spb = spk8 + (long)b * 1024 * 2048 + (m & ~63) + (m & 15);
    const int mch = (m >> 4) & 3;
    unsigned* mw = mask_ws + (long)b * 32 * 2048 + m;
    double v = 0.0;
    for (int tw = 0; tw < 32; tw++) {
        float c[32];
#pragma unroll
        for (int j = 0; j < 32; j++)
            c[j] = src[(long)(tw * 32 + j) * 2048];
        unsigned mword = 0;
#pragma unroll
        for (int j = 0; j < 32; j++) {
            v = 0.95 * v + (double)c[j];
            bool s = v >= 1.0;
            mword |= (s ? 1u : 0u) << j;
            if (s) v = 0.0;
            const int t = tw * 32 + j;
            spb[(long)t * 2048 + ((mch ^ ((t >> 1) & 3)) << 4)] = s ? 1 : 0;
        }
        mw[(long)tw * 2048] = mword;
    }
}

// masks [b][32][2048] -> f32 spikes [b][2048][1024]
__global__ __launch_bounds__(256) void expand_spk(
    const unsigned* __restrict__ mask_ws,
    float* __restrict__ spk1)
{
    __shared__ unsigned msk[8][32];
    const long rowbase = (long)blockIdx.x * 8;
    const int b = (int)(rowbase >> 11), m0 = (int)(rowbase & 2047);
    const int tid = threadIdx.x;
    {
        int w = tid >> 3, r = tid & 7;
        msk[r][w] = mask_ws[((long)b * 32 + w) * 2048 + m0 + r];
    }
    __syncthreads();
    const int r = tid >> 5, l5 = tid & 31;
    float* dst = spk1 + (rowbase + r) * 1024;
    const int sh = (l5 & 7) * 4;
#pragma unroll
    for (int j = 0; j < 8; j++) {
        const int t = l5 * 4 + j * 128;
        const unsigned w = msk[r][(l5 >> 3) + j * 4];
        float4 o;
        o.x = ((w >> sh) & 1u) ? 1.f : 0.f;
        o.y = ((w >> (sh + 1)) & 1u) ? 1.f : 0.f;
        o.z = ((w >> (sh + 2)) & 1u) ? 1.f : 0.f;
        o.w = ((w >> (sh + 3)) & 1u) ? 1.f : 0.f;
        *(float4*)&dst[t] = o;
    }
}

// LDS-chunked LIF for layer 2 (proven round 4)
template <int RPB>
__global__ __launch_bounds__(256) void lif_lds(float* __restrict__ cur)
{
    __shared__ float cs[RPB][36];
    const long rowbase = (long)blockIdx.x * RPB;
    float* base = cur + rowbase * 1024;
    const int tid = threadIdx.x;
    double v = 0.0;
    const int NV = RPB * 32 / 4;
    for (int tc = 0; tc < 1024; tc += 32) {
        for (int f = tid; f < NV; f += 256) {
            int row = f >> 3, t4 = (f & 7) * 4;
            *(float4*)&cs[row][t4] = *(const float4*)&base[(long)row * 1024 + tc + t4];
        }
        __syncthreads();
        if (tid < RPB) {
#pragma unroll
            for (int j = 0; j < 32; j++) {
                v = 0.95 * v + (double)cs[tid][j];
                bool s = v >= 1.0;
                cs[tid][j] = s ? 1.f : 0.f;
                if (s) v = 0.0;
            }
        }
        __syncthreads();
        for (int f = tid; f < NV; f += 256) {
            int row = f >> 3, t4 = (f & 7) * 4;
            *(float4*)&base[(long)row * 1024 + tc + t4] = *(float4*)&cs[row][t4];
        }
        __syncthreads();
    }
}

// ======================= fallback (round 3, proven) =======================

__device__ inline void split3(float w, _Float16& q0, _Float16& q1, _Float16& q2) {
    float p0 = rintf(w * 4096.f) * 2.44140625e-4f;
    float r1 = w - p0;
    float p1s = rintf(r1 * 8388608.f) * 2.44140625e-4f;
    float r2 = r1 - p1s * 4.8828125e-4f;
    float p2s = rintf(r2 * 1.7179869184e10f) * 1.220703125e-4f;
    q0 = (_Float16)p0; q1 = (_Float16)p1s; q2 = (_Float16)p2s;
}

__global__ __launch_bounds__(256) void gemm_f16x3_kernel(
    const float* __restrict__ A, const float* __restrict__ Bmat,
    const float* __restrict__ bias, float* __restrict__ C,
    int M, int N, int K, long sB, long sC)
{
    __shared__ _Float16 As[3][128][40];
    __shared__ _Float16 Bsh[128][40];
    const int batch = blockIdx.z;
    const float* Bp = Bmat + (long)batch * sB;
    float* Cp = C + (long)batch * sC;
    const int m0 = blockIdx.y * 128, n0 = blockIdx.x * 128;
    const int tid = threadIdx.x, lane = tid & 63, wave = tid >> 6;
    const int wrow = (wave >> 1) * 64, wcol = (wave & 1) * 64;
    const int lm = lane & 15, lq = lane >> 4;
    const int a_mo = tid >> 3, a_kc = (tid & 7) * 4;
    const int b_kq = tid >> 5, b_nq = tid & 31;

    f32x4 acc[3][4][4];
#pragma unroll
    for (int p = 0; p < 3; p++)
#pragma unroll
        for (int i = 0; i < 4; i++)
#pragma unroll
            for (int j = 0; j < 4; j++) acc[p][i][j] = (f32x4)0.f;

    for (int k0 = 0; k0 < K; k0 += 32) {
#pragma unroll
        for (int i = 0; i < 4; i++) {
            const int m = i * 32 + a_mo;
            float4 w = *(const float4*)&A[(long)(m0 + m) * K + k0 + a_kc];
            _Float16 a0[4], a1[4], a2[4];
            split3(w.x, a0[0], a1[0], a2[0]);
            split3(w.y, a0[1], a1[1], a2[1]);
            split3(w.z, a0[2], a1[2], a2[2]);
            split3(w.w, a0[3], a1[3], a2[3]);
            *(f16x4*)&As[0][m][a_kc] = (f16x4){a0[0], a0[1], a0[2], a0[3]};
            *(f16x4*)&As[1][m][a_kc] = (f16x4){a1[0], a1[1], a1[2], a1[3]};
            *(f16x4*)&As[2][m][a_kc] = (f16x4){a2[0], a2[1], a2[2], a2[3]};
        }
        {
            float4 r0 = *(const float4*)&Bp[(long)(k0 + b_kq * 4 + 0) * N + n0 + b_nq * 4];
            float4 r1 = *(const float4*)&Bp[(long)(k0 + b_kq * 4 + 1) * N + n0 + b_nq * 4];
            float4 r2 = *(const float4*)&Bp[(long)(k0 + b_kq * 4 + 2) * N + n0 + b_nq * 4];
            float4 r3 = *(const float4*)&Bp[(long)(k0 + b_kq * 4 + 3) * N + n0 + b_nq * 4];
            *(f16x4*)&Bsh[b_nq * 4 + 0][b_kq * 4] =
                (f16x4){(_Float16)r0.x, (_Float16)r1.x, (_Float16)r2.x, (_Float16)r3.x};
            *(f16x4*)&Bsh[b_nq * 4 + 1][b_kq * 4] =
                (f16x4){(_Float16)r0.y, (_Float16)r1.y, (_Float16)r2.y, (_Float16)r3.y};
            *(f16x4*)&Bsh[b_nq * 4 + 2][b_kq * 4] =
                (f16x4){(_Float16)r0.z, (_Float16)r1.z, (_Float16)r2.z, (_Float16)r3.z};
            *(f16x4*)&Bsh[b_nq * 4 + 3][b_kq * 4] =
                (f16x4){(_Float16)r0.w, (_Float16)r1.w, (_Float16)r2.w, (_Float16)r3.w};
        }
        __syncthreads();
        f16x8 bf[4];
#pragma unroll
        for (int j = 0; j < 4; j++)
            bf[j] = *(const f16x8*)&Bsh[wcol + j * 16 + lm][lq * 8];
#pragma unroll
        for (int p = 0; p < 3; p++) {
            f16x8 af[4];
#pragma unroll
            for (int i = 0; i < 4; i++)
                af[i] = *(const f16x8*)&As[p][wrow + i * 16 + lm][lq * 8];
#pragma unroll
            for (int i = 0; i < 4; i++)
#pragma unroll
                for (int j = 0; j < 4; j++)
                    acc[p][i][j] = __builtin_amdgcn_mfma_f32_16x16x32_f16(
                        af[i], bf[j], acc[p][i][j], 0, 0, 0);
        }
        __syncthreads();
    }
#pragma unroll
    for (int i = 0; i < 4; i++)
#pragma unroll
        for (int r = 0; r < 4; r++) {
            const int row = m0 + wrow + i * 16 + lq * 4 + r;
            const double bv = (double)bias[row];
#pragma unroll
            for (int j = 0; j < 4; j++) {
                double s = (double)acc[0][i][j][r]
                         + (double)acc[1][i][j][r] * 4.8828125e-4
                         + (double)acc[2][i][j][r] * 4.76837158203125e-7 + bv;
                Cp[(long)row * N + n0 + wcol + j * 16 + lm] = (float)s;
            }
        }
}

__global__ __launch_bounds__(256) void lif_rows(float* __restrict__ data,
                                                long nrows, int T)
{
    long r = (long)blockIdx.x * blockDim.x + threadIdx.x;
    if (r >= nrows) return;
    float* p = data + r * (long)T;
    double v = 0.0;
    for (int t = 0; t < T; t += 4) {
        float4 c = *(float4*)(p + t);
        float4 s;
        v = 0.95 * v + (double)c.x; s.x = (v >= 1.0) ? 1.f : 0.f; if (v >= 1.0) v = 0.0;
        v = 0.95 * v + (double)c.y; s.y = (v >= 1.0) ? 1.f : 0.f; if (v >= 1.0) v = 0.0;
        v = 0.95 * v + (double)c.z; s.z = (v >= 1.0) ? 1.f : 0.f; if (v >= 1.0) v = 0.0;
        v = 0.95 * v + (double)c.w; s.w = (v >= 1.0) ? 1.f : 0.f; if (v >= 1.0) v = 0.0;
        *(float4*)(p + t) = s;
    }
}

// ======================= launch =======================

extern "C" void kernel_launch(void* const* d_in, const int* in_sizes, int n_in,
                              void* d_out, int out_size, void* d_ws, size_t ws_size,
                              hipStream_t stream)
{
    const float* x  = (const float*)d_in[0];  // (32, 512, 1024)
    const float* w1 = (const float*)d_in[1];  // (2048, 512)
    const float* b1 = (const float*)d_in[2];  // (2048)
    const float* w2 = (const float*)d_in[3];  // (256, 2048)
    const float* b2 = (const float*)d_in[4];  // (256)

    float* out  = (float*)d_out;
    float* spk1 = out;                              // (32, 2048, 1024)
    float* spk2 = out + (long)32 * 2048 * 1024;     // (32, 256, 1024)

    const size_t WP1 = 4194304;        // [8][4][2048][64] i8
    const size_t WP2 = 2097152;        // [32][4][256][64] i8
    const size_t X8T = 16777216;       // [32][1024][512] i8
    const size_t SPK = 67108864;       // [32][1024][2048] i8
    const size_t MSK = 8388608;        // [32][32][2048] u32
    const size_t NEED = WP1 + WP2 + X8T + SPK + MSK;

    if (ws_size >= NEED) {
        char* ws = (char*)d_ws;
        signed char* wp1 = (signed char*)ws;
        signed char* wp2 = (signed char*)(ws + WP1);
        unsigned char* x8t = (unsigned char*)(ws + WP1 + WP2);
        unsigned char* spk8 = (unsigned char*)(ws + WP1 + WP2 + X8T);
        unsigned* mask_ws = (unsigned*)(ws + WP1 + WP2 + X8T + SPK);

        prep_w8<<<1024, 256, 0, stream>>>(w1, wp1, 2048, 512);
        prep_w8<<<512, 256, 0, stream>>>(w2, wp2, 256, 2048);
        prep_x8<<<dim3(16, 8, 32), 256, 0, stream>>>(x, x8t);

        // layer 1: cur1t [b][t][2048] -> coalesced LIF -> spikes
        gemm_i8<true><<<dim3(32, 8, 32), 256, 0, stream>>>(
            wp1, x8t, b1, spk1, 2048, 512);
        lif1_t<<<dim3(8, 32), 256, 0, stream>>>(spk1, spk8, mask_ws);
        expand_spk<<<8192, 256, 0, stream>>>(mask_ws, spk1);

        // layer 2: cur2 [b][256][1024] direct -> in-place LIF
        gemm_i8<false><<<dim3(8, 4, 32), 256, 0, stream>>>(
            wp2, spk8, b2, spk2, 256, 2048);
        lif_lds<128><<<64, 256, 0, stream>>>(spk2);
    } else {
        gemm_f16x3_kernel<<<dim3(8, 16, 32), 256, 0, stream>>>(
            w1, x, b1, spk1, 2048, 1024, 512, (long)512 * 1024, (long)2048 * 1024);
        lif_rows<<<(65536 + 255) / 256, 256, 0, stream>>>(spk1, 65536, 1024);
        gemm_f16x3_kernel<<<dim3(8, 2, 32), 256, 0, stream>>>(
            w2, spk1, b2, spk2, 256, 1024, 2048, (long)2048 * 1024, (long)256 * 1024);
        lif_rows<<<(8192 + 255) / 256, 256, 0, stream>>>(spk2, 8192, 1024);
    }
}

// Round 9
// 740.103 us; speedup vs baseline: 1.2174x; 1.1440x over previous
//
#include <hip/hip_runtime.h>

// ---------------------------------------------------------------------------
// LavaNetwork, bit-exact 4-plane i8 MFMA GEMM (mfma_i32_16x16x64_i8).
//   w ~ k*2^-31 (k = rint(w*2^31), residual <= 2^-32), 4 balanced base-256
//   digits -> exact i8 planes, exact i32 sums, exact i64 Horner + f64 bias.
// Round-9 structure:
//   - wave tile 32t x 32m (acc 64 AGPR) -> 3 waves/SIMD via launch_bounds(256,3)
//   - acts DIRECT to VGPR from [b][kt][t][64] layout (register double-buffer);
//     LDS holds only weights (16 KB, GLDS double-buffered, shared by 4 waves)
//   - weights keep the proven chunk swizzle c^((m>>1)&3) for conflict-free
//     ds_read_b128
// Fallback: round-3 proven f16 path if ws too small.
// ---------------------------------------------------------------------------

typedef int i32x4 __attribute__((ext_vector_type(4)));
typedef _Float16 f16x8 __attribute__((ext_vector_type(8)));
typedef _Float16 f16x4 __attribute__((ext_vector_type(4)));
typedef float f32x4 __attribute__((ext_vector_type(4)));

#define GLDS(g, l) __builtin_amdgcn_global_load_lds( \
    (const __attribute__((address_space(1))) void*)(g), \
    (__attribute__((address_space(3))) void*)(l), 16, 0, 0)

#define INV231 4.656612873077392578125e-10   // 2^-31

// ======================= prep =======================

// w (M,K) f32 -> wp [K/64][4][M][64] i8 digit planes; 16-B chunk c of row m
// stored at c ^ ((m>>1)&3)  (round-6/8-proven conflict-free for ds_read_b128).
__global__ __launch_bounds__(256) void prep_w8(const float* __restrict__ A,
                                               signed char* __restrict__ wp,
                                               int M, int K)
{
    long gt = (long)blockIdx.x * 256 + threadIdx.x;
    int kq4 = K >> 2;
    int m = (int)(gt / kq4), kq = (int)(gt % kq4);
    int k0 = kq * 4;
    int kt = k0 >> 6, kin = k0 & 63;
    int cw = ((kin >> 4) ^ (m >> 1)) & 3;
    float4 w = *(const float4*)&A[(long)m * K + k0];
    float wv[4] = {w.x, w.y, w.z, w.w};
    int pack[4] = {0, 0, 0, 0};
#pragma unroll
    for (int e = 0; e < 4; e++) {
        long k64 = (long)rint((double)wv[e] * 2147483648.0);  // * 2^31
#pragma unroll
        for (int j = 0; j < 3; j++) {
            long r = ((k64 + 128) & 255) - 128;   // balanced digit [-128,127]
            pack[j] |= ((int)r & 255) << (e * 8);
            k64 = (k64 - r) >> 8;
        }
        pack[3] |= ((int)k64 & 255) << (e * 8);
    }
#pragma unroll
    for (int p = 0; p < 4; p++)
        *(int*)&wp[(((long)kt * 4 + p) * M + m) * 64 + cw * 16 + (kin & 15)] = pack[p];
}

// x [b][512][1024] f32 -> x8t [b][8][1024][64] i8 (k-tile-major, plain layout
// for direct coalesced frag loads; no swizzle).
__global__ __launch_bounds__(256) void prep_x8(const float* __restrict__ x,
                                               unsigned char* __restrict__ xt)
{
    __shared__ float xs[64][68];
    const int b = blockIdx.z, i0 = blockIdx.y * 64, t0 = blockIdx.x * 64;
    const float* xb = x + ((long)b * 512 + i0) * 1024 + t0;
#pragma unroll
    for (int p = 0; p < 4; p++) {
        int f = threadIdx.x + p * 256;
        int i = f >> 4, t4 = (f & 15) * 4;
        *(float4*)&xs[i][t4] = *(const float4*)&xb[(long)i * 1024 + t4];
    }
    __syncthreads();
    int tt = threadIdx.x >> 2, c = threadIdx.x & 3;
    unsigned char bytes[16];
#pragma unroll
    for (int j = 0; j < 16; j++)
        bytes[j] = (unsigned char)xs[c * 16 + j][tt];
    *(uint4*)&xt[(((long)b * 8 + (i0 >> 6)) * 1024 + t0 + tt) * 64 + c * 16] =
        *(uint4*)bytes;
}

// ======================= GEMM (both orientations) =======================
// TRANS: D[t][M]  (acts A, weights B) -> cur1t for coalesced LIF
// !TRANS: D[M][t] (weights A, acts B) -> cur2 directly
// Block: 32m x 128t, 4 waves each own a 32-t slice (all share the 32-m LDS
// weight tile). Wave tile 32t x 32m, 16 MFMA / (2 glb + 8 lds) per k64.
template <bool TRANS>
__global__ __launch_bounds__(256, 3) void gemm_i8(
    const signed char* __restrict__ wp,     // [K/64][4][M][64] swizzled
    const unsigned char* __restrict__ act,  // [b][K/64][1024][64] plain
    const float* __restrict__ bias,         // (M)
    float* __restrict__ C,
    int M, int K)
{
    __shared__ signed char Ws[2][4][32][64];   // 16 KB

    const int b = blockIdx.z;
    const int m0 = blockIdx.x * 32, t0 = blockIdx.y * 128;
    const int tid = threadIdx.x, lane = tid & 63, wave = tid >> 6;
    const int wt = t0 + wave * 32;            // wave's global t base
    const int lm = lane & 15, lq = lane >> 4;
    const int fro = ((lq ^ (lm >> 1)) & 3) * 16;   // swizzled LDS read offset
    const int gl_t = lane >> 2, gl_c = (lane & 3) * 16;
    const int niter = K >> 6;

    const unsigned char* ab = act + (long)b * niter * 1024 * 64;
    // slab r for this wave: r in {wave, wave+4}: p = r>>1, s = r&1
    const int p0 = wave >> 1, s0 = wave & 1;          // slab r = wave
    const int p1 = (wave + 4) >> 1, s1 = wave & 1;    // slab r = wave+4

    i32x4 acc[4][2][2];   // [plane][A-frag][B-frag]
#pragma unroll
    for (int p = 0; p < 4; p++)
#pragma unroll
        for (int i = 0; i < 2; i++)
#pragma unroll
            for (int j = 0; j < 2; j++) acc[p][i][j] = (i32x4)0;

    // stage weights iter 0 into buf 0
    {
        const signed char* g0 = wp + (((long)p0) * M + m0 + s0 * 16 + gl_t) * 64 + gl_c;
        const signed char* g1 = wp + (((long)p1) * M + m0 + s1 * 16 + gl_t) * 64 + gl_c;
        GLDS(g0, &Ws[0][p0][s0 * 16][0]);
        GLDS(g1, &Ws[0][p1][s1 * 16][0]);
    }
    // acts iter 0 into registers
    i32x4 a0 = *(const i32x4*)&ab[((long)(wt + 0 * 16 + lm)) * 64 + lq * 16];
    i32x4 a1 = *(const i32x4*)&ab[((long)(wt + 1 * 16 + lm)) * 64 + lq * 16];
    __syncthreads();

    for (int it = 0; it < niter; it++) {
        const int buf = it & 1;
        const int nx = (it + 1 < niter) ? it + 1 : it;
        // prefetch weights it+1 -> buf^1 (GLDS) and acts it+1 -> registers;
        // both are drained by the end-of-iter barrier's vmcnt(0) anyway.
        if (it + 1 < niter) {
            const long kb = (long)(it + 1) * 4;
            const signed char* g0 =
                wp + ((kb + p0) * M + m0 + s0 * 16 + gl_t) * 64 + gl_c;
            const signed char* g1 =
                wp + ((kb + p1) * M + m0 + s1 * 16 + gl_t) * 64 + gl_c;
            GLDS(g0, &Ws[buf ^ 1][p0][s0 * 16][0]);
            GLDS(g1, &Ws[buf ^ 1][p1][s1 * 16][0]);
        }
        i32x4 an0 = *(const i32x4*)&ab[((long)nx * 1024 + wt + 0 * 16 + lm) * 64 + lq * 16];
        i32x4 an1 = *(const i32x4*)&ab[((long)nx * 1024 + wt + 1 * 16 + lm) * 64 + lq * 16];

#pragma unroll
        for (int p = 0; p < 4; p++) {
            i32x4 w0 = *(const i32x4*)&Ws[buf][p][lm][fro];
            i32x4 w1 = *(const i32x4*)&Ws[buf][p][16 + lm][fro];
            if (TRANS) {
                acc[p][0][0] = __builtin_amdgcn_mfma_i32_16x16x64_i8(a0, w0, acc[p][0][0], 0, 0, 0);
                acc[p][0][1] = __builtin_amdgcn_mfma_i32_16x16x64_i8(a0, w1, acc[p][0][1], 0, 0, 0);
                acc[p][1][0] = __builtin_amdgcn_mfma_i32_16x16x64_i8(a1, w0, acc[p][1][0], 0, 0, 0);
                acc[p][1][1] = __builtin_amdgcn_mfma_i32_16x16x64_i8(a1, w1, acc[p][1][1], 0, 0, 0);
            } else {
                acc[p][0][0] = __builtin_amdgcn_mfma_i32_16x16x64_i8(w0, a0, acc[p][0][0], 0, 0, 0);
                acc[p][0][1] = __builtin_amdgcn_mfma_i32_16x16x64_i8(w0, a1, acc[p][0][1], 0, 0, 0);
                acc[p][1][0] = __builtin_amdgcn_mfma_i32_16x16x64_i8(w1, a0, acc[p][1][0], 0, 0, 0);
                acc[p][1][1] = __builtin_amdgcn_mfma_i32_16x16x64_i8(w1, a1, acc[p][1][1], 0, 0, 0);
            }
        }
        __syncthreads();
        a0 = an0; a1 = an1;
    }

    if (TRANS) {
        // D[t][m]: acc[p][tf][mf]; col = m (lane lm), row = t (lq*4 + r)
        double bv[2];
        bv[0] = (double)bias[m0 + lm];
        bv[1] = (double)bias[m0 + 16 + lm];
        float* Cb = C + (long)b * 1024 * M;
#pragma unroll
        for (int tf = 0; tf < 2; tf++)
#pragma unroll
            for (int r = 0; r < 4; r++) {
                const int trow = wt + tf * 16 + lq * 4 + r;
#pragma unroll
                for (int mf = 0; mf < 2; mf++) {
                    long T = acc[3][tf][mf][r];
                    T = T * 256 + acc[2][tf][mf][r];
                    T = T * 256 + acc[1][tf][mf][r];
                    T = T * 256 + acc[0][tf][mf][r];
                    Cb[(long)trow * M + m0 + mf * 16 + lm] =
                        (float)((double)T * INV231 + bv[mf]);
                }
            }
    } else {
        // D[m][t]: acc[p][mf][tf]; col = t (lane lm), row = m (lq*4 + r)
        float* Cb = C + (long)b * M * 1024;
#pragma unroll
        for (int mf = 0; mf < 2; mf++)
#pragma unroll
            for (int r = 0; r < 4; r++) {
                const int mrow = m0 + mf * 16 + lq * 4 + r;
                const double bv = (double)bias[mrow];
#pragma unroll
                for (int tf = 0; tf < 2; tf++) {
                    long T = acc[3][mf][tf][r];
                    T = T * 256 + acc[2][mf][tf][r];
                    T = T * 256 + acc[1][mf][tf][r];
                    T = T * 256 + acc[0][mf][tf][r];
                    Cb[(long)mrow * 1024 + wt + tf * 16 + lm] =
                        (float)((double)T * INV231 + bv);
                }
            }
    }
}

// ======================= LIF =======================

// Coalesced thread-per-row scan over cur1t [b][1024][2048]; emits i8 spikes
// [b][32][1024][64] (k-tile-major, plain) + 1024-bit masks.
__global__ __launch_bounds__(256) void lif1_t(
    const float* __restrict__ ct,
    unsigned char* __restrict__ spk8,
    unsigned* __restrict__ mask_ws)
{
    const int b = blockIdx.y;
    const int m = blockIdx.x * 256 + threadIdx.x;
    const float* src = ct + (long)b * 1024 * 2048 + m;
    unsigned char* spb = spk8 + (((long)b * 32 + (m >> 6)) * 1024) * 64 + (m & 63);
    unsigned* mw = mask_ws + (long)b * 32 * 2048 + m;
    double v = 0.0;
    for (int tw = 0; tw < 32; tw++) {
        float c[32];
#pragma unroll
        for (int j = 0; j < 32; j++)
            c[j] = src[(long)(tw * 32 + j) * 2048];
        unsigned mword = 0;
#pragma unroll
        for (int j = 0; j < 32; j++) {
            v = 0.95 * v + (double)c[j];
            bool s = v >= 1.0;
            mword |= (s ? 1u : 0u) << j;
            if (s) v = 0.0;
            spb[(long)(tw * 32 + j) * 64] = s ? 1 : 0;
        }
        mw[(long)tw * 2048] = mword;
    }
}

// masks [b][32][2048] -> f32 spikes [b][2048][1024]
__global__ __launch_bounds__(256) void expand_spk(
    const unsigned* __restrict__ mask_ws,
    float* __restrict__ spk1)
{
    __shared__ unsigned msk[8][32];
    const long rowbase = (long)blockIdx.x * 8;
    const int b = (int)(rowbase >> 11), m0 = (int)(rowbase & 2047);
    const int tid = threadIdx.x;
    {
        int w = tid >> 3, r = tid & 7;
        msk[r][w] = mask_ws[((long)b * 32 + w) * 2048 + m0 + r];
    }
    __syncthreads();
    const int r = tid >> 5, l5 = tid & 31;
    float* dst = spk1 + (rowbase + r) * 1024;
    const int sh = (l5 & 7) * 4;
#pragma unroll
    for (int j = 0; j < 8; j++) {
        const int t = l5 * 4 + j * 128;
        const unsigned w = msk[r][(l5 >> 3) + j * 4];
        float4 o;
        o.x = ((w >> sh) & 1u) ? 1.f : 0.f;
        o.y = ((w >> (sh + 1)) & 1u) ? 1.f : 0.f;
        o.z = ((w >> (sh + 2)) & 1u) ? 1.f : 0.f;
        o.w = ((w >> (sh + 3)) & 1u) ? 1.f : 0.f;
        *(float4*)&dst[t] = o;
    }
}

// LDS-chunked LIF for layer 2 (proven round 4)
template <int RPB>
__global__ __launch_bounds__(256) void lif_lds(float* __restrict__ cur)
{
    __shared__ float cs[RPB][36];
    const long rowbase = (long)blockIdx.x * RPB;
    float* base = cur + rowbase * 1024;
    const int tid = threadIdx.x;
    double v = 0.0;
    const int NV = RPB * 32 / 4;
    for (int tc = 0; tc < 1024; tc += 32) {
        for (int f = tid; f < NV; f += 256) {
            int row = f >> 3, t4 = (f & 7) * 4;
            *(float4*)&cs[row][t4] = *(const float4*)&base[(long)row * 1024 + tc + t4];
        }
        __syncthreads();
        if (tid < RPB) {
#pragma unroll
            for (int j = 0; j < 32; j++) {
                v = 0.95 * v + (double)cs[tid][j];
                bool s = v >= 1.0;
                cs[tid][j] = s ? 1.f : 0.f;
                if (s) v = 0.0;
            }
        }
        __syncthreads();
        for (int f = tid; f < NV; f += 256) {
            int row = f >> 3, t4 = (f & 7) * 4;
            *(float4*)&base[(long)row * 1024 + tc + t4] = *(float4*)&cs[row][t4];
        }
        __syncthreads();
    }
}

// ======================= fallback (round 3, proven) =======================

__device__ inline void split3(float w, _Float16& q0, _Float16& q1, _Float16& q2) {
    float p0 = rintf(w * 4096.f) * 2.44140625e-4f;
    float r1 = w - p0;
    float p1s = rintf(r1 * 8388608.f) * 2.44140625e-4f;
    float r2 = r1 - p1s * 4.8828125e-4f;
    float p2s = rintf(r2 * 1.7179869184e10f) * 1.220703125e-4f;
    q0 = (_Float16)p0; q1 = (_Float16)p1s; q2 = (_Float16)p2s;
}

__global__ __launch_bounds__(256) void gemm_f16x3_kernel(
    const float* __restrict__ A, const float* __restrict__ Bmat,
    const float* __restrict__ bias, float* __restrict__ C,
    int M, int N, int K, long sB, long sC)
{
    __shared__ _Float16 As[3][128][40];
    __shared__ _Float16 Bsh[128][40];
    const int batch = blockIdx.z;
    const float* Bp = Bmat + (long)batch * sB;
    float* Cp = C + (long)batch * sC;
    const int m0 = blockIdx.y * 128, n0 = blockIdx.x * 128;
    const int tid = threadIdx.x, lane = tid & 63, wave = tid >> 6;
    const int wrow = (wave >> 1) * 64, wcol = (wave & 1) * 64;
    const int lm = lane & 15, lq = lane >> 4;
    const int a_mo = tid >> 3, a_kc = (tid & 7) * 4;
    const int b_kq = tid >> 5, b_nq = tid & 31;

    f32x4 acc[3][4][4];
#pragma unroll
    for (int p = 0; p < 3; p++)
#pragma unroll
        for (int i = 0; i < 4; i++)
#pragma unroll
            for (int j = 0; j < 4; j++) acc[p][i][j] = (f32x4)0.f;

    for (int k0 = 0; k0 < K; k0 += 32) {
#pragma unroll
        for (int i = 0; i < 4; i++) {
            const int m = i * 32 + a_mo;
            float4 w = *(const float4*)&A[(long)(m0 + m) * K + k0 + a_kc];
            _Float16 a0[4], a1[4], a2[4];
            split3(w.x, a0[0], a1[0], a2[0]);
            split3(w.y, a0[1], a1[1], a2[1]);
            split3(w.z, a0[2], a1[2], a2[2]);
            split3(w.w, a0[3], a1[3], a2[3]);
            *(f16x4*)&As[0][m][a_kc] = (f16x4){a0[0], a0[1], a0[2], a0[3]};
            *(f16x4*)&As[1][m][a_kc] = (f16x4){a1[0], a1[1], a1[2], a1[3]};
            *(f16x4*)&As[2][m][a_kc] = (f16x4){a2[0], a2[1], a2[2], a2[3]};
        }
        {
            float4 r0 = *(const float4*)&Bp[(long)(k0 + b_kq * 4 + 0) * N + n0 + b_nq * 4];
            float4 r1 = *(const float4*)&Bp[(long)(k0 + b_kq * 4 + 1) * N + n0 + b_nq * 4];
            float4 r2 = *(const float4*)&Bp[(long)(k0 + b_kq * 4 + 2) * N + n0 + b_nq * 4];
            float4 r3 = *(const float4*)&Bp[(long)(k0 + b_kq * 4 + 3) * N + n0 + b_nq * 4];
            *(f16x4*)&Bsh[b_nq * 4 + 0][b_kq * 4] =
                (f16x4){(_Float16)r0.x, (_Float16)r1.x, (_Float16)r2.x, (_Float16)r3.x};
            *(f16x4*)&Bsh[b_nq * 4 + 1][b_kq * 4] =
                (f16x4){(_Float16)r0.y, (_Float16)r1.y, (_Float16)r2.y, (_Float16)r3.y};
            *(f16x4*)&Bsh[b_nq * 4 + 2][b_kq * 4] =
                (f16x4){(_Float16)r0.z, (_Float16)r1.z, (_Float16)r2.z, (_Float16)r3.z};
            *(f16x4*)&Bsh[b_nq * 4 + 3][b_kq * 4] =
                (f16x4){(_Float16)r0.w, (_Float16)r1.w, (_Float16)r2.w, (_Float16)r3.w};
        }
        __syncthreads();
        f16x8 bf[4];
#pragma unroll
        for (int j = 0; j < 4; j++)
            bf[j] = *(const f16x8*)&Bsh[wcol + j * 16 + lm][lq * 8];
#pragma unroll
        for (int p = 0; p < 3; p++) {
            f16x8 af[4];
#pragma unroll
            for (int i = 0; i < 4; i++)
                af[i] = *(const f16x8*)&As[p][wrow + i * 16 + lm][lq * 8];
#pragma unroll
            for (int i = 0; i < 4; i++)
#pragma unroll
                for (int j = 0; j < 4; j++)
                    acc[p][i][j] = __builtin_amdgcn_mfma_f32_16x16x32_f16(
                        af[i], bf[j], acc[p][i][j], 0, 0, 0);
        }
        __syncthreads();
    }
#pragma unroll
    for (int i = 0; i < 4; i++)
#pragma unroll
        for (int r = 0; r < 4; r++) {
            const int row = m0 + wrow + i * 16 + lq * 4 + r;
            const double bv = (double)bias[row];
#pragma unroll
            for (int j = 0; j < 4; j++) {
                double s = (double)acc[0][i][j][r]
                         + (double)acc[1][i][j][r] * 4.8828125e-4
                         + (double)acc[2][i][j][r] * 4.76837158203125e-7 + bv;
                Cp[(long)row * N + n0 + wcol + j * 16 + lm] = (float)s;
            }
        }
}

__global__ __launch_bounds__(256) void lif_rows(float* __restrict__ data,
                                                long nrows, int T)
{
    long r = (long)blockIdx.x * blockDim.x + threadIdx.x;
    if (r >= nrows) return;
    float* p = data + r * (long)T;
    double v = 0.0;
    for (int t = 0; t < T; t += 4) {
        float4 c = *(float4*)(p + t);
        float4 s;
        v = 0.95 * v + (double)c.x; s.x = (v >= 1.0) ? 1.f : 0.f; if (v >= 1.0) v = 0.0;
        v = 0.95 * v + (double)c.y; s.y = (v >= 1.0) ? 1.f : 0.f; if (v >= 1.0) v = 0.0;
        v = 0.95 * v + (double)c.z; s.z = (v >= 1.0) ? 1.f : 0.f; if (v >= 1.0) v = 0.0;
        v = 0.95 * v + (double)c.w; s.w = (v >= 1.0) ? 1.f : 0.f; if (v >= 1.0) v = 0.0;
        *(float4*)(p + t) = s;
    }
}

// ======================= launch =======================

extern "C" void kernel_launch(void* const* d_in, const int* in_sizes, int n_in,
                              void* d_out, int out_size, void* d_ws, size_t ws_size,
                              hipStream_t stream)
{
    const float* x  = (const float*)d_in[0];  // (32, 512, 1024)
    const float* w1 = (const float*)d_in[1];  // (2048, 512)
    const float* b1 = (const float*)d_in[2];  // (2048)
    const float* w2 = (const float*)d_in[3];  // (256, 2048)
    const float* b2 = (const float*)d_in[4];  // (256)

    float* out  = (float*)d_out;
    float* spk1 = out;                              // (32, 2048, 1024)
    float* spk2 = out + (long)32 * 2048 * 1024;     // (32, 256, 1024)

    const size_t WP1 = 4194304;        // [8][4][2048][64] i8
    const size_t WP2 = 2097152;        // [32][4][256][64] i8
    const size_t X8T = 16777216;       // [32][8][1024][64] i8
    const size_t SPK = 67108864;       // [32][32][1024][64] i8
    const size_t MSK = 8388608;        // [32][32][2048] u32
    const size_t NEED = WP1 + WP2 + X8T + SPK + MSK;

    if (ws_size >= NEED) {
        char* ws = (char*)d_ws;
        signed char* wp1 = (signed char*)ws;
        signed char* wp2 = (signed char*)(ws + WP1);
        unsigned char* x8t = (unsigned char*)(ws + WP1 + WP2);
        unsigned char* spk8 = (unsigned char*)(ws + WP1 + WP2 + X8T);
        unsigned* mask_ws = (unsigned*)(ws + WP1 + WP2 + X8T + SPK);

        prep_w8<<<1024, 256, 0, stream>>>(w1, wp1, 2048, 512);
        prep_w8<<<512, 256, 0, stream>>>(w2, wp2, 256, 2048);
        prep_x8<<<dim3(16, 8, 32), 256, 0, stream>>>(x, x8t);

        // layer 1: cur1t [b][t][2048] -> coalesced LIF -> spikes
        gemm_i8<true><<<dim3(64, 8, 32), 256, 0, stream>>>(
            wp1, x8t, b1, spk1, 2048, 512);
        lif1_t<<<dim3(8, 32), 256, 0, stream>>>(spk1, spk8, mask_ws);
        expand_spk<<<8192, 256, 0, stream>>>(mask_ws, spk1);

        // layer 2: cur2 [b][256][1024] direct -> in-place LIF
        gemm_i8<false><<<dim3(8, 8, 32), 256, 0, stream>>>(
            wp2, spk8, b2, spk2, 256, 2048);
        lif_lds<128><<<64, 256, 0, stream>>>(spk2);
    } else {
        gemm_f16x3_kernel<<<dim3(8, 16, 32), 256, 0, stream>>>(
            w1, x, b1, spk1, 2048, 1024, 512, (long)512 * 1024, (long)2048 * 1024);
        lif_rows<<<(65536 + 255) / 256, 256, 0, stream>>>(spk1, 65536, 1024);
        gemm_f16x3_kernel<<<dim3(8, 2, 32), 256, 0, stream>>>(
            w2, spk1, b2, spk2, 256, 1024, 2048, (long)2048 * 1024, (long)256 * 1024);
        lif_rows<<<(8192 + 255) / 256, 256, 0, stream>>>(spk2, 8192, 1024);
    }
}